// Round 1
// 359.688 us; speedup vs baseline: 1.0369x; 1.0369x over previous
//
#include <hip/hip_runtime.h>

#define RR 8
#define TILE 32
#define EXT (TILE + 2 * RR)   // 48

typedef float f4 __attribute__((ext_vector_type(4)));

// Kernel 1: per low-res pixel A = cov/(var+eps), b = mean_y - A*mean_x via
// clamped 17x17 box sums (zero-pad OOB + analytic N). Separable with
// register sliding windows to minimize LDS instruction count.
__global__ __launch_bounds__(256) void k_ab(
    const float* __restrict__ lrx, const float* __restrict__ lry,
    float* __restrict__ Aout, float* __restrict__ Bout, int H, int W) {
  __shared__ float sx[EXT][EXT];
  __shared__ float sy[EXT][EXT];
  __shared__ float hx[EXT][TILE];
  __shared__ float hy[EXT][TILE];
  __shared__ float hxy[EXT][TILE];
  __shared__ float hxx[EXT][TILE];

  const int bc = blockIdx.z;
  const size_t plane = (size_t)bc * H * W;
  const float* __restrict__ px = lrx + plane;
  const float* __restrict__ py = lry + plane;
  const int tx0 = blockIdx.x * TILE;
  const int ty0 = blockIdx.y * TILE;
  const int tid = threadIdx.y * 32 + threadIdx.x;  // block = 32x8 = 256

  // Stage 48x48 region. Interior blocks (no clamping needed): float4 loads,
  // 576 vector items instead of 4608 scalar items. Border blocks: scalar+clamp.
  const bool interior = (tx0 >= RR) && (ty0 >= RR) &&
                        (tx0 + TILE + RR <= W) && (ty0 + TILE + RR <= H);
  if (interior) {
    const size_t base = (size_t)(ty0 - RR) * W + (tx0 - RR);
    for (int i = tid; i < EXT * (EXT / 4); i += 256) {  // 48*12 = 576
      int r = i / (EXT / 4);
      int c4 = (i - r * (EXT / 4)) * 4;
      size_t o = base + (size_t)r * W + c4;
      *(float4*)&sx[r][c4] = *(const float4*)(px + o);
      *(float4*)&sy[r][c4] = *(const float4*)(py + o);
    }
  } else {
    for (int i = tid; i < EXT * EXT; i += 256) {
      int r = i / EXT, c = i % EXT;
      int gy = ty0 + r - RR, gx = tx0 + c - RR;
      float vx = 0.f, vy = 0.f;
      if (gy >= 0 && gy < H && gx >= 0 && gx < W) {
        size_t o = (size_t)gy * W + gx;
        vx = px[o];
        vy = py[o];
      }
      sx[r][c] = vx;
      sy[r][c] = vy;
    }
  }
  __syncthreads();

  // Horizontal 17-tap sums: 48 rows x 8 groups of 4 outputs = 384 work items.
  // Each item: 5+5 ds_read_b128 (20-wide window), sliding-window 4 outputs.
  for (int q = tid; q < EXT * (TILE / 4); q += 256) {
    int r = q >> 3;
    int c0 = (q & 7) * 4;
    float xv[20], yv[20];
#pragma unroll
    for (int t = 0; t < 5; ++t) {
      float4 x4 = *(const float4*)&sx[r][c0 + 4 * t];
      float4 y4 = *(const float4*)&sy[r][c0 + 4 * t];
      xv[4 * t + 0] = x4.x; xv[4 * t + 1] = x4.y; xv[4 * t + 2] = x4.z; xv[4 * t + 3] = x4.w;
      yv[4 * t + 0] = y4.x; yv[4 * t + 1] = y4.y; yv[4 * t + 2] = y4.z; yv[4 * t + 3] = y4.w;
    }
    float pv[20], qv[20];
#pragma unroll
    for (int i = 0; i < 20; ++i) { pv[i] = xv[i] * yv[i]; qv[i] = xv[i] * xv[i]; }
    float ax = 0.f, ay = 0.f, axy = 0.f, axx = 0.f;
#pragma unroll
    for (int i = 0; i < 17; ++i) { ax += xv[i]; ay += yv[i]; axy += pv[i]; axx += qv[i]; }
    float4 ox, oy, oxy, oxx;
    ox.x = ax; oy.x = ay; oxy.x = axy; oxx.x = axx;
#pragma unroll
    for (int j = 1; j < 4; ++j) {
      ax += xv[j + 16] - xv[j - 1];
      ay += yv[j + 16] - yv[j - 1];
      axy += pv[j + 16] - pv[j - 1];
      axx += qv[j + 16] - qv[j - 1];
      (&ox.x)[j] = ax; (&oy.x)[j] = ay; (&oxy.x)[j] = axy; (&oxx.x)[j] = axx;
    }
    *(float4*)&hx[r][c0] = ox;
    *(float4*)&hy[r][c0] = oy;
    *(float4*)&hxy[r][c0] = oxy;
    *(float4*)&hxx[r][c0] = oxx;
  }
  __syncthreads();

  // Vertical 17-tap: thread (tx, ty) computes rows ty*4..ty*4+3 at col tx.
  const int c = threadIdx.x;
  const int r0 = threadIdx.y * 4;
  float vx[20], vy[20], vxy[20], vxx[20];
#pragma unroll
  for (int i = 0; i < 20; ++i) {
    vx[i] = hx[r0 + i][c];
    vy[i] = hy[r0 + i][c];
    vxy[i] = hxy[r0 + i][c];
    vxx[i] = hxx[r0 + i][c];
  }
  float sX = 0.f, sY = 0.f, sXY = 0.f, sXX = 0.f;
#pragma unroll
  for (int i = 0; i < 17; ++i) { sX += vx[i]; sY += vy[i]; sXY += vxy[i]; sXX += vxx[i]; }

  const int gx = tx0 + c;
  const int nx = min(gx + RR, W - 1) - max(gx - RR, 0) + 1;
#pragma unroll
  for (int j = 0; j < 4; ++j) {
    if (j > 0) {
      sX += vx[j + 16] - vx[j - 1];
      sY += vy[j + 16] - vy[j - 1];
      sXY += vxy[j + 16] - vxy[j - 1];
      sXX += vxx[j + 16] - vxx[j - 1];
    }
    const int gy = ty0 + r0 + j;
    const int ny = min(gy + RR, H - 1) - max(gy - RR, 0) + 1;
    float inv = 1.f / (float)(nx * ny);
    float mx = sX * inv;
    float my = sY * inv;
    float cov = sXY * inv - mx * my;
    float var = sXX * inv - mx * mx;
    float a = cov / (var + 1e-8f);
    float bv = my - a * mx;
    size_t o = plane + (size_t)gy * W + gx;
    Aout[o] = a;
    Bout[o] = bv;
  }
}

// Kernel 2: bilinear align-corners upsample of A,b fused with out = A*hr + b.
// Block = 256 threads x 4 px x 4 HR rows (4x1024 HR pixels). Since
// scy = 511/2047 ~ 0.2496, 4 consecutive HR rows touch at most LR rows
// {v, v+1, v+2}: stage those 3 RAW A/B rows in LDS (6.2 KB -> 8 blocks/CU,
// full 32-wave occupancy) and do the full bilerp per pixel in registers.
// x-index math (fx/x0/wx/li) is computed once per thread, reused by 4 rows.
// hr/out are single-use 402 MB streams: non-temporal so they don't evict
// the reused A/B rows from L2.
#define KO_LDSW 264
__global__ __launch_bounds__(256) void k_out(
    const float* __restrict__ A, const float* __restrict__ Bb,
    const float* __restrict__ hr, float* __restrict__ out,
    int hl, int wl, int Hh, int Wh) {
  __shared__ float As[3][KO_LDSW];
  __shared__ float Bs[3][KO_LDSW];

  const int yb = blockIdx.y * 4;     // first of 4 HR rows
  const int bc = blockIdx.z;
  const int xb = blockIdx.x * 1024;  // first HR pixel of this block

  const float scy = (float)(hl - 1) / (float)(Hh - 1);
  const float scx = (float)(wl - 1) / (float)(Wh - 1);

  // Base LR row for this 4-row group.
  int v;
  {
    float fy0 = (float)yb * scy;
    int t = (int)fy0;
    if (t > hl - 1) t = hl - 1;
    v = t;
  }

  // Per-row y-interp params (uniform across the block).
  int ry0[4], ry1[4];
  float wyv[4];
#pragma unroll
  for (int r = 0; r < 4; ++r) {
    float fy = (float)(yb + r) * scy;
    int y0 = (int)fy;
    if (y0 > hl - 1) y0 = hl - 1;
    int y1 = y0 + 1;
    if (y1 > hl - 1) y1 = hl - 1;
    wyv[r] = fy - (float)y0;
    ry0[r] = y0 - v;  // in {0,1}
    ry1[r] = y1 - v;  // in {0,1,2}
  }

  const int x0base = (int)((float)xb * scx);
  const size_t lrBase = (size_t)bc * hl * wl;

  // Stage raw LR rows v..v+2 (row- and col-clamped), 264 cols each.
  for (int i = threadIdx.x; i < 3 * KO_LDSW; i += 256) {
    int rr = i / KO_LDSW;  // 0..2 (magic-mul)
    int cc = i - rr * KO_LDSW;
    int xl = x0base + cc;
    if (xl > wl - 1) xl = wl - 1;
    int yr = v + rr;
    if (yr > hl - 1) yr = hl - 1;
    size_t o = lrBase + (size_t)yr * wl + xl;
    As[rr][cc] = A[o];
    Bs[rr][cc] = Bb[o];
  }
  __syncthreads();

  // Per-pixel x params, shared across the 4 rows.
  const int xg = xb + threadIdx.x * 4;
  int li[4];
  float wxv[4];
#pragma unroll
  for (int j = 0; j < 4; ++j) {
    float fx = (float)(xg + j) * scx;
    int x0 = (int)fx;
    wxv[j] = fx - (float)x0;
    li[j] = x0 - x0base;
  }

  // Issue all 4 hr loads up front (4-deep MLP), non-temporal.
  const size_t hrBase = ((size_t)bc * Hh + yb) * Wh + xg;
  f4 h[4];
#pragma unroll
  for (int r = 0; r < 4; ++r)
    h[r] = __builtin_nontemporal_load((const f4*)(hr + hrBase + (size_t)r * Wh));

#pragma unroll
  for (int r = 0; r < 4; ++r) {
    const float* __restrict__ a0 = As[ry0[r]];
    const float* __restrict__ a1 = As[ry1[r]];
    const float* __restrict__ b0 = Bs[ry0[r]];
    const float* __restrict__ b1 = Bs[ry1[r]];
    const float wy = wyv[r];
    f4 res;
#pragma unroll
    for (int j = 0; j < 4; ++j) {
      int l = li[j];
      float w = wxv[j];
      float a00 = a0[l], a01 = a0[l + 1];
      float a10 = a1[l], a11 = a1[l + 1];
      float c00 = b0[l], c01 = b0[l + 1];
      float c10 = b1[l], c11 = b1[l + 1];
      float at = a00 + (a01 - a00) * w;
      float ab = a10 + (a11 - a10) * w;
      float bt = c00 + (c01 - c00) * w;
      float bbv = c10 + (c11 - c10) * w;
      float a = at + (ab - at) * wy;
      float b = bt + (bbv - bt) * wy;
      res[j] = a * h[r][j] + b;
    }
    __builtin_nontemporal_store(res, (f4*)(out + hrBase + (size_t)r * Wh));
  }
}

extern "C" void kernel_launch(void* const* d_in, const int* in_sizes, int n_in,
                              void* d_out, int out_size, void* d_ws, size_t ws_size,
                              hipStream_t stream) {
  const float* lrx = (const float*)d_in[0];
  const float* lry = (const float*)d_in[1];
  const float* hrx = (const float*)d_in[2];
  float* out = (float*)d_out;

  const int BC = 12;  // 4 batch * 3 channels
  const int hl = 512, wl = 512;
  const int Hh = 2048, Wh = 2048;

  float* A = (float*)d_ws;
  float* B = A + (size_t)BC * hl * wl;

  dim3 g1(wl / TILE, hl / TILE, BC);
  dim3 b1(32, 8);
  k_ab<<<g1, b1, 0, stream>>>(lrx, lry, A, B, hl, wl);

  dim3 g2(Wh / 1024, Hh / 4, BC);
  dim3 b2(256);
  k_out<<<g2, b2, 0, stream>>>(A, B, hrx, out, hl, wl, Hh, Wh);
}